// Round 14
// baseline (139.220 us; speedup 1.0000x reference)
//
#include <hip/hip_runtime.h>
#include <hip/hip_bf16.h>
#include <cstdint>

#define B_  4
#define T_  2048
#define C_  768
#define H_  12
#define HD_ 64

#define AS1 __attribute__((address_space(1)))
#define AS3 __attribute__((address_space(3)))

typedef float    f32x4  __attribute__((ext_vector_type(4)));
typedef __bf16   bf16x8 __attribute__((ext_vector_type(8)));
typedef uint32_t u32x4  __attribute__((ext_vector_type(4)));

// log2(e)/8: folded into Q at GEMM1 epilogue -> softmax runs in exp2 domain.
#define QSCL 0.18033688011112042f

__device__ __forceinline__ uint16_t f2b(float f) {   // native RNE cvt
  __bf16 h = (__bf16)f;
  return __builtin_bit_cast(uint16_t, h);
}
__device__ __forceinline__ uint32_t pk2(float a, float b) {
  return (uint32_t)f2b(a) | ((uint32_t)f2b(b) << 16);
}

// ---------------- fp32 -> bf16 cast (vectorized) ----------------
__global__ void k_cvt(const float* __restrict__ in, uint16_t* __restrict__ out, int n4) {
  int i = blockIdx.x * blockDim.x + threadIdx.x;
  if (i >= n4) return;
  float4 v = ((const float4*)in)[i];
  uint2 o;
  o.x = pk2(v.x, v.y);
  o.y = pk2(v.z, v.w);
  ((uint2*)out)[i] = o;
}

// ------- transpose + cast both weights: fp32 [R][Cc] -> bf16 [Cc][R] -------
__global__ void k_tr2(const float* __restrict__ Wa, uint16_t* __restrict__ WtA,
                      const float* __restrict__ Wp, uint16_t* __restrict__ WtP) {
  __shared__ float tile[32][33];
  const int bx = blockIdx.x;
  const float* in;
  uint16_t* out;
  int Cc, n0;
  if (bx < 72) { in = Wa; out = WtA; Cc = 2304; n0 = bx * 32; }
  else         { in = Wp; out = WtP; Cc = 768;  n0 = (bx - 72) * 32; }
  const int k0 = blockIdx.y * 32;
  const int tx = threadIdx.x, ty = threadIdx.y;  // (32,8)
#pragma unroll
  for (int i = 0; i < 32; i += 8)
    tile[ty + i][tx] = in[(size_t)(k0 + ty + i) * Cc + n0 + tx];
  __syncthreads();
#pragma unroll
  for (int i = 0; i < 32; i += 8)
    out[(size_t)(n0 + ty + i) * 768 + k0 + tx] = f2b(tile[tx][ty + i]);
}

// ---------------- MFMA bf16 GEMM (unchanged from r13) ----------------
template <int EPI>
__global__ __launch_bounds__(256, 3) void k_gemm(
    const uint16_t* __restrict__ A, const uint16_t* __restrict__ Bt,
    const float* __restrict__ bias, float* __restrict__ outF,
    uint16_t* __restrict__ outQKV, int M, int N, int K, int nY) {
  __shared__ __align__(16) uint16_t As[3][128 * 32];
  __shared__ __align__(16) uint16_t Bs[3][128 * 32];
  const int nwg = gridDim.x;
  const int bid = blockIdx.x;
  const int wgid = (bid & 7) * (nwg >> 3) + (bid >> 3);
  const int wy = wgid % nY, wx = wgid / nY;

  const int tid  = threadIdx.x;
  const int lane = tid & 63;
  const int wave = tid >> 6;
  const int wrow = (wave >> 1) * 64, wcol = (wave & 1) * 64;
  const int rowBase = wx * 128, colBase = wy * 128;
  const int l16 = lane & 15, kg = lane >> 4;

  f32x4 acc[4][4];
#pragma unroll
  for (int i = 0; i < 4; ++i)
#pragma unroll
    for (int j = 0; j < 4; ++j) acc[i][j] = (f32x4){0.f, 0.f, 0.f, 0.f};

  const int srow  = lane >> 2;
  const int sslot = lane & 3;
  const int ssw   = (sslot ^ (srow & 3)) << 3;

  auto STAGE = [&](int buf, int k0) {
#pragma unroll
    for (int i = 0; i < 2; ++i) {
      const int r = i * 64 + wave * 16 + srow;
      const uint16_t* srcA = A  + (size_t)(rowBase + r) * K + k0 + ssw;
      const uint16_t* srcB = Bt + (size_t)(colBase + r) * K + k0 + ssw;
      uint16_t* dstA = &As[buf][(i * 64 + wave * 16) * 32];
      uint16_t* dstB = &Bs[buf][(i * 64 + wave * 16) * 32];
      __builtin_amdgcn_global_load_lds((const AS1 uint32_t*)srcA, (AS3 uint32_t*)dstA, 16, 0, 0);
      __builtin_amdgcn_global_load_lds((const AS1 uint32_t*)srcB, (AS3 uint32_t*)dstB, 16, 0, 0);
    }
  };

  const int sA = (kg ^ (l16 & 3)) << 3;

  STAGE(0, 0);
  if (32 < K) STAGE(1, 32);
  int t = 0;
  for (int k0 = 0; k0 < K; k0 += 32, ++t) {
    if (k0 + 32 < K) {
      asm volatile("s_waitcnt vmcnt(4)" ::: "memory");
    } else {
      asm volatile("s_waitcnt vmcnt(0)" ::: "memory");
    }
    __builtin_amdgcn_sched_barrier(0);
    __builtin_amdgcn_s_barrier();

    if (k0 + 64 < K) STAGE((t + 2) % 3, k0 + 64);

    const int cb = t % 3;
    bf16x8 af[4], bfv[4];
#pragma unroll
    for (int mi = 0; mi < 4; ++mi)
      af[mi] = *(const bf16x8*)&As[cb][(wrow + mi * 16 + l16) * 32 + sA];
#pragma unroll
    for (int nj = 0; nj < 4; ++nj)
      bfv[nj] = *(const bf16x8*)&Bs[cb][(wcol + nj * 16 + l16) * 32 + sA];
#pragma unroll
    for (int mi = 0; mi < 4; ++mi)
#pragma unroll
      for (int nj = 0; nj < 4; ++nj)
        acc[mi][nj] = __builtin_amdgcn_mfma_f32_16x16x32_bf16(af[mi], bfv[nj], acc[mi][nj], 0, 0, 0);
  }

  const int rg = lane >> 4;
#pragma unroll
  for (int mi = 0; mi < 4; ++mi)
#pragma unroll
    for (int nj = 0; nj < 4; ++nj) {
      int c = colBase + wcol + nj * 16 + l16;
      float bv = bias[c];
      if (EPI == 0) {
#pragma unroll
        for (int jj = 0; jj < 4; ++jj) {
          int r = rowBase + wrow + mi * 16 + rg * 4 + jj;
          outF[(size_t)r * N + c] = acc[mi][nj][jj] + bv;
        }
      } else {
        int sel = c / 768;
        int rem = c - sel * 768;
        int head = rem >> 6, d = rem & 63;
        int r0 = rowBase + wrow + mi * 16 + rg * 4;
        int bb = r0 >> 11, tt0 = r0 & 2047;
        if (sel == 2) {
          size_t off = (((size_t)2 * (B_ * H_) + bb * H_ + head) * HD_ + d) * T_ + tt0;
          uint2 w;
          w.x = pk2(acc[mi][nj][0] + bv, acc[mi][nj][1] + bv);
          w.y = pk2(acc[mi][nj][2] + bv, acc[mi][nj][3] + bv);
          *(uint2*)&outQKV[off] = w;
        } else {
          float scl = (sel == 0) ? QSCL : 1.0f;
#pragma unroll
          for (int jj = 0; jj < 4; ++jj) {
            size_t off = (((size_t)sel * (B_ * H_) + bb * H_ + head) * T_ + tt0 + jj) * HD_ + d;
            outQKV[off] = f2b((acc[mi][nj][jj] + bv) * scl);
          }
        }
      }
    }
}

// ---------------- MFMA flash attention, v12: KVBLK=128 ----------------
// Halve the visit count (33 -> 17): each visit processes a 128-kv tile; wave
// kh owns a 64-kv half (8 QK + 8 PV + 2 l MFMA, 16 exp2 per visit). K/V are
// SINGLE-buffered (stage->wait->barrier->compute; other 2 resident blocks
// cover the staging latency) keeping LDS at exactly 48 KB -> 3 blocks/CU,
// 768 blocks co-resident in one round. Visits remain perfectly pair-balanced
// (17 for every px). P = tight 16x32 words per wave, XOR-word-swizzled.
__global__ __launch_bounds__(512, 6) void k_attn2(
    const uint16_t* __restrict__ Qb, const uint16_t* __restrict__ Kb,
    const uint16_t* __restrict__ Vb, uint16_t* __restrict__ Y) {
  __shared__ __align__(16) uint16_t Ks[128 * 64];   // [kv][d], 8 16B-slots/row
  __shared__ __align__(16) uint16_t Vs[64 * 128];   // [d][kv], 16 16B-slots/row
  __shared__ __align__(16) uint32_t Pw[8][16 * 32]; // per-wave P: 16 q x 64 kv
  const int tid  = threadIdx.x;
  const int lane = tid & 63;
  const int wq   = tid >> 6;           // wave 0..7
  const int qw   = wq & 3;             // q sub-block
  const int kh   = wq >> 2;            // kv half (64 kv each)
  const int l16  = lane & 15, kg = lane >> 4;
  const int l7   = l16 & 7;

  const int idx = blockIdx.x;
  const int tq  = idx >> 3;
  const int px  = tq & 15;
  const int g   = (idx & 7) + 8 * (tq >> 4);
  const int h = g % H_, b = g / H_;
  const size_t headBase = ((size_t)(b * H_ + h)) * (size_t)(T_ * HD_);

  // staging indices: K rows (tid>>3)+c*64, 8 slots; V rows (tid>>4)+c*32, 16 slots
  const int krow  = tid >> 3;          // 0..63
  const int kslot = tid & 7;
  const int vrow  = tid >> 4;          // 0..31
  const int vslot = tid & 15;

  const int swz = l7 << 2;             // P word-swizzle field

  uint32_t* pw = &Pw[wq][0];
  uint16_t* dstK0 = &Ks[(wq * 8) * 64];
  uint16_t* dstK1 = &Ks[(64 + wq * 8) * 64];
  uint16_t* dstV0 = &Vs[(wq * 4) * 128];
  uint16_t* dstV1 = &Vs[(32 + wq * 4) * 128];

  // constant ones A-fragment for the l-summing MFMA
  u32x4 onesw;
  onesw[0] = 0x3f803f80u; onesw[1] = 0x3f803f80u;
  onesw[2] = 0x3f803f80u; onesw[3] = 0x3f803f80u;
  const bf16x8 onesf = __builtin_bit_cast(bf16x8, onesw);

  // per-lane invariant source offsets (swizzled)
  const uint16_t* kpA = Kb + headBase + (size_t)krow * HD_ + ((kslot ^ (krow & 7)) << 3);
  const uint16_t* kpB = Kb + headBase + (size_t)(64 + krow) * HD_ + ((kslot ^ ((64 + krow) & 7)) << 3);
  const uint16_t* vpA = Vb + headBase + (size_t)vrow * T_ + ((vslot ^ (vrow & 7)) << 3);
  const uint16_t* vpB = Vb + headBase + (size_t)(32 + vrow) * T_ + ((vslot ^ ((32 + vrow) & 7)) << 3);

  for (int part = 0; part < 2; ++part) {
    const int qb = part ? (31 - px) : px;
    const int qrow0 = qb * 64 + qw * 16;

    bf16x8 qf[2];
    {
      const uint16_t* qp = Qb + headBase + (size_t)(qrow0 + l16) * HD_;
      qf[0] = *(const bf16x8*)(qp + kg * 8);
      qf[1] = *(const bf16x8*)(qp + 32 + kg * 8);
    }

    f32x4 o[4];
#pragma unroll
    for (int i = 0; i < 4; ++i) o[i] = (f32x4){0.f, 0.f, 0.f, 0.f};
    f32x4 lq = (f32x4){0.f, 0.f, 0.f, 0.f};   // l accumulator (ones-MFMA)

    const int nt = (qb >> 1) + 1;              // 128-kv tiles

    for (int t = 0; t < nt; ++t) {
      __builtin_amdgcn_s_barrier();            // (A) prior visit's reads done
      {                                        // stage tile t (4 loads/thread)
        const size_t koff = (size_t)(t * 128) * HD_;
        const size_t voff = (size_t)(t * 128);
        __builtin_amdgcn_global_load_lds((const AS1 uint32_t*)(kpA + koff), (AS3 uint32_t*)dstK0, 16, 0, 0);
        __builtin_amdgcn_global_load_lds((const AS1 uint32_t*)(kpB + koff), (AS3 uint32_t*)dstK1, 16, 0, 0);
        __builtin_amdgcn_global_load_lds((const AS1 uint32_t*)(vpA + voff), (AS3 uint32_t*)dstV0, 16, 0, 0);
        __builtin_amdgcn_global_load_lds((const AS1 uint32_t*)(vpB + voff), (AS3 uint32_t*)dstV1, 16, 0, 0);
      }
      asm volatile("s_waitcnt vmcnt(0)" ::: "memory");
      __builtin_amdgcn_sched_barrier(0);
      __builtin_amdgcn_s_barrier();            // (B) tile t visible to all

      // --- S^T: sm[nj][jj] = S[kv = kh*64+nj*16+kg*4+jj][q = l16] ---
      f32x4 sm[4];
      __builtin_amdgcn_s_setprio(1);
#pragma unroll
      for (int nj = 0; nj < 4; ++nj) {
        f32x4 acc = (f32x4){0.f, 0.f, 0.f, 0.f};
        const int row = kh * 64 + nj * 16 + l16;
#pragma unroll
        for (int kc = 0; kc < 2; ++kc) {
          const int s = (((kc * 4 + kg) ^ l7) << 3);
          bf16x8 kf = *(const bf16x8*)&Ks[row * 64 + s];
          acc = __builtin_amdgcn_mfma_f32_16x16x32_bf16(kf, qf[kc], acc, 0, 0, 0);
        }
        sm[nj] = acc;
      }
      __builtin_amdgcn_s_setprio(0);

      if (t == nt - 1) {  // diagonal tile: causal mask
        const int kvb = t * 128 + kh * 64 + kg * 4;
        const int qg  = qrow0 + l16;
#pragma unroll
        for (int nj = 0; nj < 4; ++nj)
#pragma unroll
          for (int jj = 0; jj < 4; ++jj)
            if (kvb + nj * 16 + jj > qg) sm[nj][jj] = -__builtin_inff();
      }

      // --- softmax numerator: p = exp2(S) (scale cancels in O/l) ---
#pragma unroll
      for (int nj = 0; nj < 4; ++nj)
#pragma unroll
        for (int jj = 0; jj < 4; ++jj)
          sm[nj][jj] = __builtin_exp2f(sm[nj][jj]);

      // --- P -> private LDS (row q=l16, 64 kv = 32 words, XOR-swizzled) ---
#pragma unroll
      for (int nj = 0; nj < 4; ++nj) {
        uint2 w;
        w.x = pk2(sm[nj][0], sm[nj][1]);
        w.y = pk2(sm[nj][2], sm[nj][3]);
        const int cs = (nj * 8 + kg * 2) ^ swz;
        *(uint2*)&pw[l16 * 32 + cs] = w;
      }

      // --- O^T(partial) += V^T[:, my half] P ; l via ones-MFMA ---
      __builtin_amdgcn_s_setprio(1);
#pragma unroll
      for (int kc = 0; kc < 2; ++kc) {
        const int cr = (kc * 16 + kg * 4) ^ swz;
        bf16x8 pa = *(const bf16x8*)&pw[l16 * 32 + cr];
#pragma unroll
        for (int njd = 0; njd < 4; ++njd) {
          const int row = njd * 16 + l16;
          const int s = (((kh * 8 + kc * 4 + kg) ^ l7) << 3);
          bf16x8 vf = *(const bf16x8*)&Vs[row * 128 + s];
          o[njd] = __builtin_amdgcn_mfma_f32_16x16x32_bf16(vf, pa, o[njd], 0, 0, 0);
        }
        lq = __builtin_amdgcn_mfma_f32_16x16x32_bf16(onesf, pa, lq, 0, 0, 0);
      }
      __builtin_amdgcn_s_setprio(0);
    }

    // --- combine kv-half partials via K/V LDS, then store ---
    float l_ = lq[0];                    // every lane holds l(q=l16) partial

    __syncthreads();                     // all visits' LDS reads done
    f32x4* cO = (f32x4*)&Ks[0];          // 16 KB
    float*  cL = (float*)&Vs[0];
    if (kh) {
#pragma unroll
      for (int njd = 0; njd < 4; ++njd) cO[(njd * 4 + qw) * 64 + lane] = o[njd];
      if (lane < 16) cL[qw * 64 + lane] = l_;
    }
    __syncthreads();
    if (!kh) {
      float lsum = l_ + cL[qw * 64 + l16];
      float inv = __builtin_amdgcn_rcpf(lsum);
      const int q = qrow0 + l16;
      uint16_t* yp = Y + ((size_t)(b * T_ + q)) * C_ + h * HD_ + kg * 4;
#pragma unroll
      for (int njd = 0; njd < 4; ++njd) {
        f32x4 oc = o[njd] + cO[(njd * 4 + qw) * 64 + lane];
        uint2 w;
        w.x = pk2(oc[0] * inv, oc[1] * inv);
        w.y = pk2(oc[2] * inv, oc[3] * inv);
        *(uint2*)(yp + njd * 16) = w;
      }
    }
    __syncthreads();                     // combine reads done before next part's stage
  }
}

extern "C" void kernel_launch(void* const* d_in, const int* in_sizes, int n_in,
                              void* d_out, int out_size, void* d_ws, size_t ws_size,
                              hipStream_t stream) {
  const float* x      = (const float*)d_in[0];
  const float* W_attn = (const float*)d_in[1];
  const float* b_attn = (const float*)d_in[2];
  const float* W_proj = (const float*)d_in[3];
  const float* b_proj = (const float*)d_in[4];
  float* out = (float*)d_out;

  char* ws = (char*)d_ws;
  uint16_t* xb  = (uint16_t*)(ws);
  uint16_t* WtA = (uint16_t*)(ws + 12582912);
  uint16_t* WtP = (uint16_t*)(ws + 16121856);
  uint16_t* QKV = (uint16_t*)(ws + 17301504);
  uint16_t* Yb  = (uint16_t*)(ws + 55050240);

  uint16_t* Qp = QKV;                // pre-scaled by QSCL
  uint16_t* Kp = QKV + 6291456;
  uint16_t* Vp = QKV + 12582912;     // [B,H,64,T]

  k_cvt<<<6144, 256, 0, stream>>>(x, xb, 1572864);
  k_tr2<<<dim3(96, 24), dim3(32, 8), 0, stream>>>(W_attn, WtA, W_proj, WtP);
  k_gemm<1><<<1152, 256, 0, stream>>>(xb, WtA, b_attn, nullptr, QKV, 8192, 2304, 768, 18);
  k_attn2<<<768, 512, 0, stream>>>(Qp, Kp, Vp, Yb);
  k_gemm<0><<<384, 256, 0, stream>>>(Yb, WtP, b_proj, out, nullptr, 8192, 768, 768, 6);
}